// Round 5
// baseline (1183.564 us; speedup 1.0000x reference)
//
#include <hip/hip_runtime.h>
#include <hip/hip_bf16.h>

// ---------------------------------------------------------------------------
// Stage A: _x = x @ W_down + b_down    [N,256]@[256,64] -> [N,64]
// Wd staged in LDS once per block (R2). 8 nodes/block. (unchanged)
// ---------------------------------------------------------------------------
#define KD_NODES 8
__global__ __launch_bounds__(256) void k_down(
    const float* __restrict__ x, const float* __restrict__ Wd,
    const float* __restrict__ bd, float* __restrict__ xp, int N)
{
    __shared__ float xs[KD_NODES][256];   // 8 KB
    __shared__ float4 Ws[64 * 64];        // 64 KB: Ws[pb*64+c] = Wd[4pb+q][c]
    int n0 = blockIdx.x * KD_NODES;
    int tid = threadIdx.x;

    for (int t = tid; t < KD_NODES * 256; t += 256) {
        int rr = t >> 8, kk = t & 255;
        int n = n0 + rr;
        xs[rr][kk] = (n < N) ? x[(size_t)n * 256 + kk] : 0.f;
    }
    for (int t = tid; t < 64 * 64; t += 256) {
        int pb = t >> 6, c = t & 63;
        float4 w;
        w.x = Wd[(4 * pb + 0) * 64 + c];
        w.y = Wd[(4 * pb + 1) * 64 + c];
        w.z = Wd[(4 * pb + 2) * 64 + c];
        w.w = Wd[(4 * pb + 3) * 64 + c];
        Ws[t] = w;
    }
    __syncthreads();

    int c = tid & 63;
    int r0 = (tid >> 6) * 2;
    float a0 = bd[c], a1 = a0;
    for (int pb = 0; pb < 64; pb++) {
        float4 w = Ws[pb * 64 + c];
        const float4 x0 = *(const float4*)&xs[r0][pb * 4];
        const float4 x1 = *(const float4*)&xs[r0 + 1][pb * 4];
        a0 += x0.x * w.x + x0.y * w.y + x0.z * w.z + x0.w * w.w;
        a1 += x1.x * w.x + x1.y * w.y + x1.z * w.z + x1.w * w.w;
    }
    int n = n0 + r0;
    if (n < N)     xp[(size_t)n * 64 + c]       = a0;
    if (n + 1 < N) xp[(size_t)(n + 1) * 64 + c] = a1;
}

// ---------------------------------------------------------------------------
// Stage B: CSR build + per-node gather (R3). Unchanged.
// ---------------------------------------------------------------------------
__global__ __launch_bounds__(256) void k_hist(
    const int* __restrict__ iidx, int* __restrict__ counts, int E)
{
    int e = blockIdx.x * 256 + threadIdx.x;
    if (e < E) atomicAdd(&counts[iidx[e]], 1);
}

__global__ __launch_bounds__(1024) void k_scan(
    const int* __restrict__ counts, int* __restrict__ rowptr,
    int* __restrict__ cursor, int N)
{
    __shared__ int part[1024];
    int t = threadIdx.x;
    int chunk = (N + 1023) / 1024;
    int beg = t * chunk;
    int end = min(beg + chunk, N);
    int s = 0;
    for (int i = beg; i < end; i++) s += counts[i];
    part[t] = s;
    __syncthreads();
    for (int off = 1; off < 1024; off <<= 1) {
        int v = (t >= off) ? part[t - off] : 0;
        __syncthreads();
        part[t] += v;
        __syncthreads();
    }
    int run = (t == 0) ? 0 : part[t - 1];
    for (int i = beg; i < end; i++) {
        rowptr[i] = run;
        cursor[i] = run;
        run += counts[i];
    }
    if (t == 1023) rowptr[N] = part[1023];
}

__global__ __launch_bounds__(256) void k_scatter_ids(
    const int* __restrict__ iidx, int* __restrict__ cursor,
    int* __restrict__ edge_id, int E)
{
    int e = blockIdx.x * 256 + threadIdx.x;
    if (e < E) {
        int pos = atomicAdd(&cursor[iidx[e]], 1);
        edge_id[pos] = e;
    }
}

__global__ __launch_bounds__(256) void k_gather(
    const float* __restrict__ xp, const float* __restrict__ rbf,
    const float* __restrict__ factor, const float* __restrict__ sph0,
    const float* __restrict__ sph1, const int* __restrict__ jidx,
    const int* __restrict__ rowptr, const int* __restrict__ edge_id,
    float* __restrict__ agg0, float* __restrict__ agg1,
    float* __restrict__ aggh, int N)
{
    int n = blockIdx.x * 4 + (threadIdx.x >> 6);
    if (n >= N) return;
    int p = threadIdx.x & 63;
    int beg = rowptr[n], end = rowptr[n + 1];

    float a0 = 0.f;
    float a1x = 0.f, a1y = 0.f, a1z = 0.f;
    float h0 = 0.f, h1 = 0.f, h2 = 0.f, h3 = 0.f, h4 = 0.f;

    int k = beg;
    for (; k + 1 < end; k += 2) {
        int e0 = edge_id[k], e1 = edge_id[k + 1];
        int j0 = jidx[e0], j1 = jidx[e1];
        float f0 = factor[e0], f1 = factor[e1];
        float v0 = xp[(size_t)j0 * 64 + p] * rbf[(size_t)e0 * 64 + p] * f0;
        float v1 = xp[(size_t)j1 * 64 + p] * rbf[(size_t)e1 * 64 + p] * f1;
        a0 += v0 + v1;
        a1x += v0 * sph1[e0 * 3 + 0] + v1 * sph1[e1 * 3 + 0];
        a1y += v0 * sph1[e0 * 3 + 1] + v1 * sph1[e1 * 3 + 1];
        a1z += v0 * sph1[e0 * 3 + 2] + v1 * sph1[e1 * 3 + 2];
        h0  += v0 * sph0[e0 * 5 + 0] + v1 * sph0[e1 * 5 + 0];
        h1  += v0 * sph0[e0 * 5 + 1] + v1 * sph0[e1 * 5 + 1];
        h2  += v0 * sph0[e0 * 5 + 2] + v1 * sph0[e1 * 5 + 2];
        h3  += v0 * sph0[e0 * 5 + 3] + v1 * sph0[e1 * 5 + 3];
        h4  += v0 * sph0[e0 * 5 + 4] + v1 * sph0[e1 * 5 + 4];
    }
    if (k < end) {
        int e0 = edge_id[k];
        int j0 = jidx[e0];
        float f0 = factor[e0];
        float v0 = xp[(size_t)j0 * 64 + p] * rbf[(size_t)e0 * 64 + p] * f0;
        a0 += v0;
        a1x += v0 * sph1[e0 * 3 + 0];
        a1y += v0 * sph1[e0 * 3 + 1];
        a1z += v0 * sph1[e0 * 3 + 2];
        h0  += v0 * sph0[e0 * 5 + 0];
        h1  += v0 * sph0[e0 * 5 + 1];
        h2  += v0 * sph0[e0 * 5 + 2];
        h3  += v0 * sph0[e0 * 5 + 3];
        h4  += v0 * sph0[e0 * 5 + 4];
    }

    agg0[(size_t)n * 64 + p] = a0;
    agg1[((size_t)n * 3 + 0) * 64 + p] = a1x;
    agg1[((size_t)n * 3 + 1) * 64 + p] = a1y;
    agg1[((size_t)n * 3 + 2) * 64 + p] = a1z;
    aggh[((size_t)n * 5 + 0) * 64 + p] = h0;
    aggh[((size_t)n * 5 + 1) * 64 + p] = h1;
    aggh[((size_t)n * 5 + 2) * 64 + p] = h2;
    aggh[((size_t)n * 5 + 3) * 64 + p] = h3;
    aggh[((size_t)n * 5 + 4) * 64 + p] = h4;
}

// ---------------------------------------------------------------------------
// Stage C1: node features -> node[N,384]
// R4 fix: R2 dropped the min-waves arg of __launch_bounds__ -> 236 VGPRs,
// and 72 KB LDS -> 2 blocks/CU; occupancy 10%, 270 us. Now: 8 nodes/block
// (tiles 20 KB + Ws 32 KB = 52 KB -> 3 blocks/CU) + __launch_bounds__(256,4)
// (cap 128 VGPRs -> 4 waves/SIMD). 12 waves/CU.
// ---------------------------------------------------------------------------
#define C1_NODES 8
__global__ __launch_bounds__(256, 4) void k_node(
    const float* __restrict__ xp, const float* __restrict__ agg0,
    const float* __restrict__ agg1, const float* __restrict__ aggh,
    const float* __restrict__ Wu0, const float* __restrict__ bu0,
    const float* __restrict__ Wu1, const float* __restrict__ Wuh,
    float* __restrict__ node, int N)
{
    __shared__ float xs[C1_NODES * 64];        // 2 KB
    __shared__ float a0s[C1_NODES * 64];       // 2 KB
    __shared__ float a1s[C1_NODES * 3 * 64];   // 6 KB
    __shared__ float ahs[C1_NODES * 5 * 64];   // 10 KB
    __shared__ float4 Ws[16 * 128];            // 32 KB: Ws[pb*128+c] = W[4pb+q][c]
    int n0 = blockIdx.x * C1_NODES;
    int tid = threadIdx.x;

    for (int t = tid; t < C1_NODES * 64; t += 256) {
        int n = n0 + (t >> 6);
        xs[t] = (n < N) ? xp[(size_t)n * 64 + (t & 63)] : 0.f;
    }
    __syncthreads();
    for (int t = tid; t < C1_NODES * 64; t += 256) {
        int n = n0 + (t >> 6);
        a0s[t] = (n < N) ? xs[t] * agg0[(size_t)n * 64 + (t & 63)] : 0.f;
    }
    for (int t = tid; t < C1_NODES * 192; t += 256) {
        int r = t / 192, rem = t - r * 192;
        int n = n0 + r;
        a1s[t] = (n < N) ? xs[r * 64 + (rem & 63)] * agg1[(size_t)n * 192 + rem] : 0.f;
    }
    for (int t = tid; t < C1_NODES * 320; t += 256) {
        int r = t / 320, rem = t - r * 320;
        int n = n0 + r;
        ahs[t] = (n < N) ? xs[r * 64 + (rem & 63)] * aggh[(size_t)n * 320 + rem] : 0.f;
    }
    for (int t = tid; t < 16 * 128; t += 256) {
        int pb = t >> 7, cc = t & 127;
        float4 w;
        w.x = Wu0[(4 * pb + 0) * 128 + cc];
        w.y = Wu0[(4 * pb + 1) * 128 + cc];
        w.z = Wu0[(4 * pb + 2) * 128 + cc];
        w.w = Wu0[(4 * pb + 3) * 128 + cc];
        Ws[t] = w;
    }
    __syncthreads();

    int c = tid & 63;              // owns cols c and c+64 (of 128)
    int r0 = (tid >> 6) * 2;       // 2 rows per thread (of 8)

    // ---- l0 ----
    {
        float A0[2], A1[2];
        float b0 = bu0[c], b1 = bu0[c + 64];
#pragma unroll
        for (int r = 0; r < 2; r++) { A0[r] = b0; A1[r] = b1; }
        for (int pb = 0; pb < 16; pb++) {
            const float4 w0 = Ws[pb * 128 + c];
            const float4 w1 = Ws[pb * 128 + c + 64];
#pragma unroll
            for (int r = 0; r < 2; r++) {
                const float4 av = *(const float4*)&a0s[(r0 + r) * 64 + pb * 4];
                A0[r] += av.x * w0.x + av.y * w0.y + av.z * w0.z + av.w * w0.w;
                A1[r] += av.x * w1.x + av.y * w1.y + av.z * w1.z + av.w * w1.w;
            }
        }
#pragma unroll
        for (int r = 0; r < 2; r++) {
            int n = n0 + r0 + r;
            if (n < N) {
                node[(size_t)n * 384 + c]      = A0[r];
                node[(size_t)n * 384 + c + 64] = A1[r];
            }
        }
    }
    __syncthreads();
    for (int t = tid; t < 16 * 128; t += 256) {
        int pb = t >> 7, cc = t & 127;
        float4 w;
        w.x = Wu1[(4 * pb + 0) * 128 + cc];
        w.y = Wu1[(4 * pb + 1) * 128 + cc];
        w.z = Wu1[(4 * pb + 2) * 128 + cc];
        w.w = Wu1[(4 * pb + 3) * 128 + cc];
        Ws[t] = w;
    }
    __syncthreads();
    // ---- l1 ----
    {
        float S0[2], S1[2];
#pragma unroll
        for (int r = 0; r < 2; r++) { S0[r] = 0.f; S1[r] = 0.f; }
        for (int cc = 0; cc < 3; cc++) {
            float D0[2], D1[2];
#pragma unroll
            for (int r = 0; r < 2; r++) { D0[r] = 0.f; D1[r] = 0.f; }
            for (int pb = 0; pb < 16; pb++) {
                const float4 w0 = Ws[pb * 128 + c];
                const float4 w1 = Ws[pb * 128 + c + 64];
#pragma unroll
                for (int r = 0; r < 2; r++) {
                    const float4 av = *(const float4*)&a1s[((r0 + r) * 3 + cc) * 64 + pb * 4];
                    D0[r] += av.x * w0.x + av.y * w0.y + av.z * w0.z + av.w * w0.w;
                    D1[r] += av.x * w1.x + av.y * w1.y + av.z * w1.z + av.w * w1.w;
                }
            }
#pragma unroll
            for (int r = 0; r < 2; r++) { S0[r] += D0[r] * D0[r]; S1[r] += D1[r] * D1[r]; }
        }
#pragma unroll
        for (int r = 0; r < 2; r++) {
            int n = n0 + r0 + r;
            if (n < N) {
                node[(size_t)n * 384 + 128 + c]      = S0[r];
                node[(size_t)n * 384 + 128 + c + 64] = S1[r];
            }
        }
    }
    __syncthreads();
    for (int t = tid; t < 16 * 128; t += 256) {
        int pb = t >> 7, cc = t & 127;
        float4 w;
        w.x = Wuh[(4 * pb + 0) * 128 + cc];
        w.y = Wuh[(4 * pb + 1) * 128 + cc];
        w.z = Wuh[(4 * pb + 2) * 128 + cc];
        w.w = Wuh[(4 * pb + 3) * 128 + cc];
        Ws[t] = w;
    }
    __syncthreads();
    // ---- lh ----
    {
        float S0[2], S1[2];
#pragma unroll
        for (int r = 0; r < 2; r++) { S0[r] = 0.f; S1[r] = 0.f; }
        for (int cc = 0; cc < 5; cc++) {
            float D0[2], D1[2];
#pragma unroll
            for (int r = 0; r < 2; r++) { D0[r] = 0.f; D1[r] = 0.f; }
            for (int pb = 0; pb < 16; pb++) {
                const float4 w0 = Ws[pb * 128 + c];
                const float4 w1 = Ws[pb * 128 + c + 64];
#pragma unroll
                for (int r = 0; r < 2; r++) {
                    const float4 av = *(const float4*)&ahs[((r0 + r) * 5 + cc) * 64 + pb * 4];
                    D0[r] += av.x * w0.x + av.y * w0.y + av.z * w0.z + av.w * w0.w;
                    D1[r] += av.x * w1.x + av.y * w1.y + av.z * w1.z + av.w * w1.w;
                }
            }
#pragma unroll
            for (int r = 0; r < 2; r++) { S0[r] += D0[r] * D0[r]; S1[r] += D1[r] * D1[r]; }
        }
#pragma unroll
        for (int r = 0; r < 2; r++) {
            int n = n0 + r0 + r;
            if (n < N) {
                node[(size_t)n * 384 + 256 + c]      = S0[r];
                node[(size_t)n * 384 + 256 + c + 64] = S1[r];
            }
        }
    }
}

// ---------------------------------------------------------------------------
// Stage C2 (fused): t = node@W_n1+b_n1; h = silu(LN(t)); out = h@W_n2+b_n2+x
// R4 fix: was re-reading all 655 KB of Wn1/Wn2 from global per wave and
// carrying 64 accumulator regs. Now: 16 rows/block, thread = 2 cols x 8 rows,
// weight k-slices staged in a reused 32 KB LDS buffer. LDS ~52 KB ->
// 3 blocks/CU; __launch_bounds__(256,4) caps VGPR at 128.
// ---------------------------------------------------------------------------
#define C2_ROWS 16
__global__ __launch_bounds__(256, 4) void k_final(
    const float* __restrict__ node, const float* __restrict__ Wn1,
    const float* __restrict__ bn1, const float* __restrict__ lng,
    const float* __restrict__ lnb, const float* __restrict__ Wn2,
    const float* __restrict__ bn2, const float* __restrict__ x,
    float* __restrict__ out, int N)
{
    __shared__ float As[C2_ROWS][32];      // 2 KB
    __shared__ float Hs[C2_ROWS][256];     // 16 KB
    __shared__ float4 Wsl[8 * 256];        // 32 KB: Wsl[pb*256+col] = W[k0+4pb+q][col]
    __shared__ float red[C2_ROWS][16];     // 1 KB
    __shared__ float red2[C2_ROWS][16];    // 1 KB
    __shared__ float mstat[C2_ROWS][2];

    int n0 = blockIdx.x * C2_ROWS;
    int tid = threadIdx.x;
    int c2 = tid & 127;        // owns cols c2 and c2+128
    int g = tid >> 7;
    int r0 = g * 8;            // 8 rows per thread

    float acc0[8], acc1[8];
#pragma unroll
    for (int r = 0; r < 8; r++) { acc0[r] = 0.f; acc1[r] = 0.f; }

    for (int k0 = 0; k0 < 384; k0 += 32) {
        for (int t = tid; t < C2_ROWS * 32; t += 256) {
            int r = t >> 5, k = t & 31;
            int n = n0 + r;
            As[r][k] = (n < N) ? node[(size_t)n * 384 + k0 + k] : 0.f;
        }
        for (int t = tid; t < 8 * 256; t += 256) {
            int pb = t >> 8, col = t & 255;
            float4 w;
            w.x = Wn1[(size_t)(k0 + 4 * pb + 0) * 256 + col];
            w.y = Wn1[(size_t)(k0 + 4 * pb + 1) * 256 + col];
            w.z = Wn1[(size_t)(k0 + 4 * pb + 2) * 256 + col];
            w.w = Wn1[(size_t)(k0 + 4 * pb + 3) * 256 + col];
            Wsl[t] = w;
        }
        __syncthreads();
        for (int pb = 0; pb < 8; pb++) {
            const float4 w0 = Wsl[pb * 256 + c2];
            const float4 w1 = Wsl[pb * 256 + c2 + 128];
#pragma unroll
            for (int r = 0; r < 8; r++) {
                const float4 av = *(const float4*)&As[r0 + r][pb * 4];
                acc0[r] += av.x * w0.x + av.y * w0.y + av.z * w0.z + av.w * w0.w;
                acc1[r] += av.x * w1.x + av.y * w1.y + av.z * w1.z + av.w * w1.w;
            }
        }
        __syncthreads();
    }

    // pre-LN values into Hs
    {
        float b0 = bn1[c2], b1 = bn1[c2 + 128];
#pragma unroll
        for (int r = 0; r < 8; r++) {
            Hs[r0 + r][c2]       = acc0[r] + b0;
            Hs[r0 + r][c2 + 128] = acc1[r] + b1;
        }
    }
    __syncthreads();

    // per-row mean / var (16 threads per row, 16 floats each)
    {
        int row = tid >> 4, seg = tid & 15;
        float s = 0.f, s2 = 0.f;
#pragma unroll
        for (int k = 0; k < 16; k += 4) {
            const float4 v = *(const float4*)&Hs[row][seg * 16 + k];
            s  += v.x + v.y + v.z + v.w;
            s2 += v.x * v.x + v.y * v.y + v.z * v.z + v.w * v.w;
        }
        red[row][seg] = s;
        red2[row][seg] = s2;
    }
    __syncthreads();
    if (tid < C2_ROWS) {
        float s = 0.f, s2 = 0.f;
#pragma unroll
        for (int q = 0; q < 16; q++) { s += red[tid][q]; s2 += red2[tid][q]; }
        float m = s * (1.f / 256.f);
        float var = s2 * (1.f / 256.f) - m * m;
        mstat[tid][0] = m;
        mstat[tid][1] = rsqrtf(var + 1e-5f);
    }
    __syncthreads();

    // LN + SiLU in place
    {
        float g0 = lng[c2], g1 = lng[c2 + 128];
        float bb0 = lnb[c2], bb1 = lnb[c2 + 128];
#pragma unroll
        for (int r = 0; r < 8; r++) {
            int row = r0 + r;
            float m = mstat[row][0], is = mstat[row][1];
            float z0 = (Hs[row][c2] - m) * is * g0 + bb0;
            float z1 = (Hs[row][c2 + 128] - m) * is * g1 + bb1;
            Hs[row][c2]       = z0 / (1.f + __expf(-z0));
            Hs[row][c2 + 128] = z1 / (1.f + __expf(-z1));
        }
    }
    __syncthreads();

    // GEMM2: out = h @ W_n2 + b_n2 + x   (h rows live in Hs)
    float o0[8], o1[8];
#pragma unroll
    for (int r = 0; r < 8; r++) { o0[r] = 0.f; o1[r] = 0.f; }
    for (int k0 = 0; k0 < 256; k0 += 32) {
        for (int t = tid; t < 8 * 256; t += 256) {
            int pb = t >> 8, col = t & 255;
            float4 w;
            w.x = Wn2[(size_t)(k0 + 4 * pb + 0) * 256 + col];
            w.y = Wn2[(size_t)(k0 + 4 * pb + 1) * 256 + col];
            w.z = Wn2[(size_t)(k0 + 4 * pb + 2) * 256 + col];
            w.w = Wn2[(size_t)(k0 + 4 * pb + 3) * 256 + col];
            Wsl[t] = w;
        }
        __syncthreads();
        for (int pb = 0; pb < 8; pb++) {
            const float4 w0 = Wsl[pb * 256 + c2];
            const float4 w1 = Wsl[pb * 256 + c2 + 128];
#pragma unroll
            for (int r = 0; r < 8; r++) {
                const float4 av = *(const float4*)&Hs[r0 + r][k0 + pb * 4];
                o0[r] += av.x * w0.x + av.y * w0.y + av.z * w0.z + av.w * w0.w;
                o1[r] += av.x * w1.x + av.y * w1.y + av.z * w1.z + av.w * w1.w;
            }
        }
        __syncthreads();
    }
    {
        float ob0 = bn2[c2], ob1 = bn2[c2 + 128];
#pragma unroll
        for (int r = 0; r < 8; r++) {
            int n = n0 + r0 + r;
            if (n < N) {
                out[(size_t)n * 256 + c2]       = o0[r] + ob0 + x[(size_t)n * 256 + c2];
                out[(size_t)n * 256 + c2 + 128] = o1[r] + ob1 + x[(size_t)n * 256 + c2 + 128];
            }
        }
    }
}

// ---------------------------------------------------------------------------
extern "C" void kernel_launch(void* const* d_in, const int* in_sizes, int n_in,
                              void* d_out, int out_size, void* d_ws, size_t ws_size,
                              hipStream_t stream)
{
    const float* x      = (const float*)d_in[0];
    const float* rbf    = (const float*)d_in[1];
    const float* factor = (const float*)d_in[2];
    const float* sph0   = (const float*)d_in[3];
    const float* sph1   = (const float*)d_in[4];
    const float* Wd     = (const float*)d_in[5];
    const float* bd     = (const float*)d_in[6];
    const float* Wu0    = (const float*)d_in[7];
    const float* bu0    = (const float*)d_in[8];
    const float* Wu1    = (const float*)d_in[9];
    const float* Wuh    = (const float*)d_in[10];
    const float* Wn1    = (const float*)d_in[11];
    const float* bn1    = (const float*)d_in[12];
    const float* lng    = (const float*)d_in[13];
    const float* lnb    = (const float*)d_in[14];
    const float* Wn2    = (const float*)d_in[15];
    const float* bn2    = (const float*)d_in[16];
    const int*   jidx   = (const int*)d_in[17];
    const int*   iidx   = (const int*)d_in[18];
    float* out = (float*)d_out;

    int N = in_sizes[0] / 256;
    int E = in_sizes[17];

    float* ws   = (float*)d_ws;
    float* xp   = ws;                        // [N,64]
    float* agg0 = xp   + (size_t)N * 64;     // [N,64]
    float* agg1 = agg0 + (size_t)N * 64;     // [N,3,64]
    float* aggh = agg1 + (size_t)N * 192;    // [N,5,64]
    float* node = aggh + (size_t)N * 320;    // [N,384]

    // CSR scratch aliased onto the node buffer (dead before k_node writes it).
    int* counts  = (int*)node;               // [N]
    int* rowptr  = counts + (N + 1);         // [N+1]
    int* cursor  = rowptr + (N + 1);         // [N]
    int* edge_id = cursor + (N + 1);         // [E]

    hipMemsetAsync(counts, 0, (size_t)(N + 1) * sizeof(int), stream);

    k_down<<<dim3((N + KD_NODES - 1) / KD_NODES), dim3(256), 0, stream>>>(
        x, Wd, bd, xp, N);
    k_hist<<<dim3((E + 255) / 256), dim3(256), 0, stream>>>(iidx, counts, E);
    k_scan<<<dim3(1), dim3(1024), 0, stream>>>(counts, rowptr, cursor, N);
    k_scatter_ids<<<dim3((E + 255) / 256), dim3(256), 0, stream>>>(
        iidx, cursor, edge_id, E);
    k_gather<<<dim3((N + 3) / 4), dim3(256), 0, stream>>>(
        xp, rbf, factor, sph0, sph1, jidx, rowptr, edge_id,
        agg0, agg1, aggh, N);
    k_node<<<dim3((N + C1_NODES - 1) / C1_NODES), dim3(256), 0, stream>>>(
        xp, agg0, agg1, aggh, Wu0, bu0, Wu1, Wuh, node, N);
    k_final<<<dim3((N + C2_ROWS - 1) / C2_ROWS), dim3(256), 0, stream>>>(
        node, Wn1, bn1, lng, lnb, Wn2, bn2, x, out, N);
}

// Round 6
// 795.723 us; speedup vs baseline: 1.4874x; 1.4874x over previous
//
#include <hip/hip_runtime.h>
#include <hip/hip_bf16.h>

typedef __attribute__((ext_vector_type(8))) short bf16x8;
typedef __attribute__((ext_vector_type(4))) float f32x4;

__device__ __forceinline__ unsigned short f2bf(float f) {
    unsigned u = __float_as_uint(f);
    return (unsigned short)((u + 0x7FFF + ((u >> 16) & 1)) >> 16);  // RNE
}
__device__ __forceinline__ unsigned pack2(float a, float b) {
    return (unsigned)f2bf(a) | ((unsigned)f2bf(b) << 16);
}

// ---------------------------------------------------------------------------
// Stage A: _x = x @ W_down + b_down    [N,256]@[256,64] -> [N,64]  (unchanged)
// ---------------------------------------------------------------------------
#define KD_NODES 8
__global__ __launch_bounds__(256) void k_down(
    const float* __restrict__ x, const float* __restrict__ Wd,
    const float* __restrict__ bd, float* __restrict__ xp, int N)
{
    __shared__ float xs[KD_NODES][256];
    __shared__ float4 Ws[64 * 64];
    int n0 = blockIdx.x * KD_NODES;
    int tid = threadIdx.x;

    for (int t = tid; t < KD_NODES * 256; t += 256) {
        int rr = t >> 8, kk = t & 255;
        int n = n0 + rr;
        xs[rr][kk] = (n < N) ? x[(size_t)n * 256 + kk] : 0.f;
    }
    for (int t = tid; t < 64 * 64; t += 256) {
        int pb = t >> 6, c = t & 63;
        float4 w;
        w.x = Wd[(4 * pb + 0) * 64 + c];
        w.y = Wd[(4 * pb + 1) * 64 + c];
        w.z = Wd[(4 * pb + 2) * 64 + c];
        w.w = Wd[(4 * pb + 3) * 64 + c];
        Ws[t] = w;
    }
    __syncthreads();

    int c = tid & 63;
    int r0 = (tid >> 6) * 2;
    float a0 = bd[c], a1 = a0;
    for (int pb = 0; pb < 64; pb++) {
        float4 w = Ws[pb * 64 + c];
        const float4 x0 = *(const float4*)&xs[r0][pb * 4];
        const float4 x1 = *(const float4*)&xs[r0 + 1][pb * 4];
        a0 += x0.x * w.x + x0.y * w.y + x0.z * w.z + x0.w * w.w;
        a1 += x1.x * w.x + x1.y * w.y + x1.z * w.z + x1.w * w.w;
    }
    int n = n0 + r0;
    if (n < N)     xp[(size_t)n * 64 + c]       = a0;
    if (n + 1 < N) xp[(size_t)(n + 1) * 64 + c] = a1;
}

// ---------------------------------------------------------------------------
// Stage B: CSR build + per-node gather. R5: gather unrolled 4x (more loads in
// flight; edge_id->jidx/factor/rbf is a 2-level dependent chain).
// ---------------------------------------------------------------------------
__global__ __launch_bounds__(256) void k_hist(
    const int* __restrict__ iidx, int* __restrict__ counts, int E)
{
    int e = blockIdx.x * 256 + threadIdx.x;
    if (e < E) atomicAdd(&counts[iidx[e]], 1);
}

__global__ __launch_bounds__(1024) void k_scan(
    const int* __restrict__ counts, int* __restrict__ rowptr,
    int* __restrict__ cursor, int N)
{
    __shared__ int part[1024];
    int t = threadIdx.x;
    int chunk = (N + 1023) / 1024;
    int beg = t * chunk;
    int end = min(beg + chunk, N);
    int s = 0;
    for (int i = beg; i < end; i++) s += counts[i];
    part[t] = s;
    __syncthreads();
    for (int off = 1; off < 1024; off <<= 1) {
        int v = (t >= off) ? part[t - off] : 0;
        __syncthreads();
        part[t] += v;
        __syncthreads();
    }
    int run = (t == 0) ? 0 : part[t - 1];
    for (int i = beg; i < end; i++) {
        rowptr[i] = run;
        cursor[i] = run;
        run += counts[i];
    }
    if (t == 1023) rowptr[N] = part[1023];
}

__global__ __launch_bounds__(256) void k_scatter_ids(
    const int* __restrict__ iidx, int* __restrict__ cursor,
    int* __restrict__ edge_id, int E)
{
    int e = blockIdx.x * 256 + threadIdx.x;
    if (e < E) {
        int pos = atomicAdd(&cursor[iidx[e]], 1);
        edge_id[pos] = e;
    }
}

__global__ __launch_bounds__(256) void k_gather(
    const float* __restrict__ xp, const float* __restrict__ rbf,
    const float* __restrict__ factor, const float* __restrict__ sph0,
    const float* __restrict__ sph1, const int* __restrict__ jidx,
    const int* __restrict__ rowptr, const int* __restrict__ edge_id,
    float* __restrict__ agg0, float* __restrict__ agg1,
    float* __restrict__ aggh, int N)
{
    int n = blockIdx.x * 4 + (threadIdx.x >> 6);
    if (n >= N) return;
    int p = threadIdx.x & 63;
    int beg = rowptr[n], end = rowptr[n + 1];

    float a0 = 0.f;
    float a1x = 0.f, a1y = 0.f, a1z = 0.f;
    float h0 = 0.f, h1 = 0.f, h2 = 0.f, h3 = 0.f, h4 = 0.f;

    int k = beg;
    for (; k + 3 < end; k += 4) {
        int e0 = edge_id[k], e1 = edge_id[k + 1];
        int e2 = edge_id[k + 2], e3 = edge_id[k + 3];
        int j0 = jidx[e0], j1 = jidx[e1], j2 = jidx[e2], j3 = jidx[e3];
        float f0 = factor[e0], f1 = factor[e1], f2 = factor[e2], f3 = factor[e3];
        float x0 = xp[(size_t)j0 * 64 + p], r0 = rbf[(size_t)e0 * 64 + p];
        float x1 = xp[(size_t)j1 * 64 + p], r1 = rbf[(size_t)e1 * 64 + p];
        float x2 = xp[(size_t)j2 * 64 + p], r2 = rbf[(size_t)e2 * 64 + p];
        float x3 = xp[(size_t)j3 * 64 + p], r3 = rbf[(size_t)e3 * 64 + p];
        float v0 = x0 * r0 * f0, v1 = x1 * r1 * f1;
        float v2 = x2 * r2 * f2, v3 = x3 * r3 * f3;
        a0 += (v0 + v1) + (v2 + v3);
        a1x += v0 * sph1[e0 * 3 + 0] + v1 * sph1[e1 * 3 + 0]
             + v2 * sph1[e2 * 3 + 0] + v3 * sph1[e3 * 3 + 0];
        a1y += v0 * sph1[e0 * 3 + 1] + v1 * sph1[e1 * 3 + 1]
             + v2 * sph1[e2 * 3 + 1] + v3 * sph1[e3 * 3 + 1];
        a1z += v0 * sph1[e0 * 3 + 2] + v1 * sph1[e1 * 3 + 2]
             + v2 * sph1[e2 * 3 + 2] + v3 * sph1[e3 * 3 + 2];
        h0  += v0 * sph0[e0 * 5 + 0] + v1 * sph0[e1 * 5 + 0]
             + v2 * sph0[e2 * 5 + 0] + v3 * sph0[e3 * 5 + 0];
        h1  += v0 * sph0[e0 * 5 + 1] + v1 * sph0[e1 * 5 + 1]
             + v2 * sph0[e2 * 5 + 1] + v3 * sph0[e3 * 5 + 1];
        h2  += v0 * sph0[e0 * 5 + 2] + v1 * sph0[e1 * 5 + 2]
             + v2 * sph0[e2 * 5 + 2] + v3 * sph0[e3 * 5 + 2];
        h3  += v0 * sph0[e0 * 5 + 3] + v1 * sph0[e1 * 5 + 3]
             + v2 * sph0[e2 * 5 + 3] + v3 * sph0[e3 * 5 + 3];
        h4  += v0 * sph0[e0 * 5 + 4] + v1 * sph0[e1 * 5 + 4]
             + v2 * sph0[e2 * 5 + 4] + v3 * sph0[e3 * 5 + 4];
    }
    for (; k < end; k++) {
        int e0 = edge_id[k];
        int j0 = jidx[e0];
        float f0 = factor[e0];
        float v0 = xp[(size_t)j0 * 64 + p] * rbf[(size_t)e0 * 64 + p] * f0;
        a0 += v0;
        a1x += v0 * sph1[e0 * 3 + 0];
        a1y += v0 * sph1[e0 * 3 + 1];
        a1z += v0 * sph1[e0 * 3 + 2];
        h0  += v0 * sph0[e0 * 5 + 0];
        h1  += v0 * sph0[e0 * 5 + 1];
        h2  += v0 * sph0[e0 * 5 + 2];
        h3  += v0 * sph0[e0 * 5 + 3];
        h4  += v0 * sph0[e0 * 5 + 4];
    }

    agg0[(size_t)n * 64 + p] = a0;
    agg1[((size_t)n * 3 + 0) * 64 + p] = a1x;
    agg1[((size_t)n * 3 + 1) * 64 + p] = a1y;
    agg1[((size_t)n * 3 + 2) * 64 + p] = a1z;
    aggh[((size_t)n * 5 + 0) * 64 + p] = h0;
    aggh[((size_t)n * 5 + 1) * 64 + p] = h1;
    aggh[((size_t)n * 5 + 2) * 64 + p] = h2;
    aggh[((size_t)n * 5 + 3) * 64 + p] = h3;
    aggh[((size_t)n * 5 + 4) * 64 + p] = h4;
}

// ---------------------------------------------------------------------------
// Stage C1: node features -> node[N,384]  (R4 version, proven; unchanged)
// ---------------------------------------------------------------------------
#define C1_NODES 8
__global__ __launch_bounds__(256, 4) void k_node(
    const float* __restrict__ xp, const float* __restrict__ agg0,
    const float* __restrict__ agg1, const float* __restrict__ aggh,
    const float* __restrict__ Wu0, const float* __restrict__ bu0,
    const float* __restrict__ Wu1, const float* __restrict__ Wuh,
    float* __restrict__ node, int N)
{
    __shared__ float xs[C1_NODES * 64];
    __shared__ float a0s[C1_NODES * 64];
    __shared__ float a1s[C1_NODES * 3 * 64];
    __shared__ float ahs[C1_NODES * 5 * 64];
    __shared__ float4 Ws[16 * 128];
    int n0 = blockIdx.x * C1_NODES;
    int tid = threadIdx.x;

    for (int t = tid; t < C1_NODES * 64; t += 256) {
        int n = n0 + (t >> 6);
        xs[t] = (n < N) ? xp[(size_t)n * 64 + (t & 63)] : 0.f;
    }
    __syncthreads();
    for (int t = tid; t < C1_NODES * 64; t += 256) {
        int n = n0 + (t >> 6);
        a0s[t] = (n < N) ? xs[t] * agg0[(size_t)n * 64 + (t & 63)] : 0.f;
    }
    for (int t = tid; t < C1_NODES * 192; t += 256) {
        int r = t / 192, rem = t - r * 192;
        int n = n0 + r;
        a1s[t] = (n < N) ? xs[r * 64 + (rem & 63)] * agg1[(size_t)n * 192 + rem] : 0.f;
    }
    for (int t = tid; t < C1_NODES * 320; t += 256) {
        int r = t / 320, rem = t - r * 320;
        int n = n0 + r;
        ahs[t] = (n < N) ? xs[r * 64 + (rem & 63)] * aggh[(size_t)n * 320 + rem] : 0.f;
    }
    for (int t = tid; t < 16 * 128; t += 256) {
        int pb = t >> 7, cc = t & 127;
        float4 w;
        w.x = Wu0[(4 * pb + 0) * 128 + cc];
        w.y = Wu0[(4 * pb + 1) * 128 + cc];
        w.z = Wu0[(4 * pb + 2) * 128 + cc];
        w.w = Wu0[(4 * pb + 3) * 128 + cc];
        Ws[t] = w;
    }
    __syncthreads();

    int c = tid & 63;
    int r0 = (tid >> 6) * 2;

    {
        float A0[2], A1[2];
        float b0 = bu0[c], b1 = bu0[c + 64];
#pragma unroll
        for (int r = 0; r < 2; r++) { A0[r] = b0; A1[r] = b1; }
        for (int pb = 0; pb < 16; pb++) {
            const float4 w0 = Ws[pb * 128 + c];
            const float4 w1 = Ws[pb * 128 + c + 64];
#pragma unroll
            for (int r = 0; r < 2; r++) {
                const float4 av = *(const float4*)&a0s[(r0 + r) * 64 + pb * 4];
                A0[r] += av.x * w0.x + av.y * w0.y + av.z * w0.z + av.w * w0.w;
                A1[r] += av.x * w1.x + av.y * w1.y + av.z * w1.z + av.w * w1.w;
            }
        }
#pragma unroll
        for (int r = 0; r < 2; r++) {
            int n = n0 + r0 + r;
            if (n < N) {
                node[(size_t)n * 384 + c]      = A0[r];
                node[(size_t)n * 384 + c + 64] = A1[r];
            }
        }
    }
    __syncthreads();
    for (int t = tid; t < 16 * 128; t += 256) {
        int pb = t >> 7, cc = t & 127;
        float4 w;
        w.x = Wu1[(4 * pb + 0) * 128 + cc];
        w.y = Wu1[(4 * pb + 1) * 128 + cc];
        w.z = Wu1[(4 * pb + 2) * 128 + cc];
        w.w = Wu1[(4 * pb + 3) * 128 + cc];
        Ws[t] = w;
    }
    __syncthreads();
    {
        float S0[2], S1[2];
#pragma unroll
        for (int r = 0; r < 2; r++) { S0[r] = 0.f; S1[r] = 0.f; }
        for (int cc = 0; cc < 3; cc++) {
            float D0[2], D1[2];
#pragma unroll
            for (int r = 0; r < 2; r++) { D0[r] = 0.f; D1[r] = 0.f; }
            for (int pb = 0; pb < 16; pb++) {
                const float4 w0 = Ws[pb * 128 + c];
                const float4 w1 = Ws[pb * 128 + c + 64];
#pragma unroll
                for (int r = 0; r < 2; r++) {
                    const float4 av = *(const float4*)&a1s[((r0 + r) * 3 + cc) * 64 + pb * 4];
                    D0[r] += av.x * w0.x + av.y * w0.y + av.z * w0.z + av.w * w0.w;
                    D1[r] += av.x * w1.x + av.y * w1.y + av.z * w1.z + av.w * w1.w;
                }
            }
#pragma unroll
            for (int r = 0; r < 2; r++) { S0[r] += D0[r] * D0[r]; S1[r] += D1[r] * D1[r]; }
        }
#pragma unroll
        for (int r = 0; r < 2; r++) {
            int n = n0 + r0 + r;
            if (n < N) {
                node[(size_t)n * 384 + 128 + c]      = S0[r];
                node[(size_t)n * 384 + 128 + c + 64] = S1[r];
            }
        }
    }
    __syncthreads();
    for (int t = tid; t < 16 * 128; t += 256) {
        int pb = t >> 7, cc = t & 127;
        float4 w;
        w.x = Wuh[(4 * pb + 0) * 128 + cc];
        w.y = Wuh[(4 * pb + 1) * 128 + cc];
        w.z = Wuh[(4 * pb + 2) * 128 + cc];
        w.w = Wuh[(4 * pb + 3) * 128 + cc];
        Ws[t] = w;
    }
    __syncthreads();
    {
        float S0[2], S1[2];
#pragma unroll
        for (int r = 0; r < 2; r++) { S0[r] = 0.f; S1[r] = 0.f; }
        for (int cc = 0; cc < 5; cc++) {
            float D0[2], D1[2];
#pragma unroll
            for (int r = 0; r < 2; r++) { D0[r] = 0.f; D1[r] = 0.f; }
            for (int pb = 0; pb < 16; pb++) {
                const float4 w0 = Ws[pb * 128 + c];
                const float4 w1 = Ws[pb * 128 + c + 64];
#pragma unroll
                for (int r = 0; r < 2; r++) {
                    const float4 av = *(const float4*)&ahs[((r0 + r) * 5 + cc) * 64 + pb * 4];
                    D0[r] += av.x * w0.x + av.y * w0.y + av.z * w0.z + av.w * w0.w;
                    D1[r] += av.x * w1.x + av.y * w1.y + av.z * w1.z + av.w * w1.w;
                }
            }
#pragma unroll
            for (int r = 0; r < 2; r++) { S0[r] += D0[r] * D0[r]; S1[r] += D1[r] * D1[r]; }
        }
#pragma unroll
        for (int r = 0; r < 2; r++) {
            int n = n0 + r0 + r;
            if (n < N) {
                node[(size_t)n * 384 + 256 + c]      = S0[r];
                node[(size_t)n * 384 + 256 + c + 64] = S1[r];
            }
        }
    }
}

// ---------------------------------------------------------------------------
// R5: pre-swizzle Wn1/Wn2 (f32, row-major [K][256]) into bf16 MFMA B-fragment
// order: Bsw[((ks*16+ct)*64+lane)*8 + j] = bf16(W[ks*32+(lane>>4)*8+j][ct*16+(lane&15)]).
// One-time; L2-resident output read directly as coalesced 16 B B-frags.
// ---------------------------------------------------------------------------
__global__ __launch_bounds__(256) void k_swz(
    const float* __restrict__ W, unsigned short* __restrict__ Bsw, int K)
{
    int idx = blockIdx.x * 256 + threadIdx.x;
    int total = (K >> 5) * 1024;            // (K/32) * 16 ct * 64 lanes
    if (idx >= total) return;
    int lane = idx & 63;
    int ct = (idx >> 6) & 15;
    int ks = idx >> 10;
    int col = ct * 16 + (lane & 15);
    int kbase = (ks << 5) + ((lane >> 4) << 3);
    const float* p = &W[(size_t)kbase * 256 + col];
    uint4 o;
    o.x = pack2(p[0 * 256], p[1 * 256]);
    o.y = pack2(p[2 * 256], p[3 * 256]);
    o.z = pack2(p[4 * 256], p[5 * 256]);
    o.w = pack2(p[6 * 256], p[7 * 256]);
    *(uint4*)&Bsw[(size_t)idx * 8] = o;
}

// ---------------------------------------------------------------------------
// Stage C2 (R5 rewrite): bf16 MFMA. 32 rows/block, 256 thr = 4 waves; wave w
// owns row-tile rt=w&1 and col-tiles cg*8..cg*8+7 (cg=w>>1) -> 8 mfma accs.
// GEMM1 (K=384, 12 ks) -> LN stats straight from accumulators (small padded
// LDS reduction, no f32 Hs round-trip) -> LN+SiLU -> bf16 A-tile in LDS ->
// GEMM2 (K=256, 8 ks) -> +bias+residual store. B-frags are direct global
// 16 B loads from the pre-swizzled L2-resident Bsw1/Bsw2.
// LDS: A 24.5 KB + red 8.5 KB -> 5 blocks/CU.
// A-tile row pads (+8 bf16) make frag ds_reads 2-way aliased (free, m136).
// ---------------------------------------------------------------------------
__global__ __launch_bounds__(256, 4) void k_final(
    const float* __restrict__ node, const unsigned short* __restrict__ Bsw1,
    const float* __restrict__ bn1, const float* __restrict__ lng,
    const float* __restrict__ lnb, const unsigned short* __restrict__ Bsw2,
    const float* __restrict__ bn2, const float* __restrict__ x,
    float* __restrict__ out, int N)
{
    __shared__ unsigned short Abf[32 * 392];   // GEMM1 A [32][384+8]; reused as GEMM2 A [32][256+8]
    __shared__ float red[32][33];
    __shared__ float red2[32][33];
    __shared__ float mstat[32][2];

    int n0 = blockIdx.x * 32;
    int tid = threadIdx.x;
    int lane = tid & 63;
    int w = tid >> 6;
    int rt = w & 1;
    int cg = w >> 1;
    int lcol = lane & 15;
    int quad = lane >> 4;
    int arow = rt * 16 + lcol;       // A-frag row this lane reads
    int kq = quad * 8;               // A/B-frag k sub-offset

    // ---- stage node tile as bf16 -> Abf[32][392] ----
    for (int i = tid; i < 32 * 192; i += 256) {
        int r = i / 192, c2 = i - r * 192;
        int n = n0 + r;
        float2 v;
        if (n < N) v = *(const float2*)&node[(size_t)n * 384 + 2 * c2];
        else { v.x = 0.f; v.y = 0.f; }
        *(unsigned*)&Abf[r * 392 + 2 * c2] = pack2(v.x, v.y);
    }
    __syncthreads();

    // ---- GEMM1: T = node @ Wn1 ----
    f32x4 acc[8];
#pragma unroll
    for (int t = 0; t < 8; t++) acc[t] = (f32x4){0.f, 0.f, 0.f, 0.f};
    for (int ks = 0; ks < 12; ks++) {
        bf16x8 a = *(const bf16x8*)&Abf[arow * 392 + ks * 32 + kq];
        const bf16x8* bp =
            (const bf16x8*)&Bsw1[(size_t)(((ks * 16 + cg * 8) * 64) + lane) * 8];
#pragma unroll
        for (int t = 0; t < 8; t++)
            acc[t] = __builtin_amdgcn_mfma_f32_16x16x32_bf16(a, bp[t * 64], acc[t], 0, 0, 0);
    }

    // ---- per-row LN stats from accumulators (D layout: row=rt*16+quad*4+q, col=ct*16+lcol)
    float bias[8];
#pragma unroll
    for (int t = 0; t < 8; t++) bias[t] = bn1[cg * 128 + t * 16 + lcol];
#pragma unroll
    for (int q = 0; q < 4; q++) {
        float s = 0.f, s2 = 0.f;
#pragma unroll
        for (int t = 0; t < 8; t++) {
            float v = acc[t][q] + bias[t];
            s += v; s2 += v * v;
        }
        int row = rt * 16 + quad * 4 + q;
        red[row][cg * 16 + lcol] = s;
        red2[row][cg * 16 + lcol] = s2;
    }
    __syncthreads();
    if (tid < 32) {
        float s = 0.f, s2 = 0.f;
#pragma unroll
        for (int u = 0; u < 32; u++) { s += red[tid][u]; s2 += red2[tid][u]; }
        float m = s * (1.f / 256.f);
        float var = s2 * (1.f / 256.f) - m * m;
        mstat[tid][0] = m;
        mstat[tid][1] = rsqrtf(var + 1e-5f);
    }
    __syncthreads();

    // ---- LN + SiLU, write h as bf16 GEMM2 A-tile [32][264] (Abf reuse safe:
    // all GEMM1 A-reads completed before the stats barrier) ----
#pragma unroll
    for (int t = 0; t < 8; t++) {
        int col = cg * 128 + t * 16 + lcol;
        float gg = lng[col], bb = lnb[col];
#pragma unroll
        for (int q = 0; q < 4; q++) {
            int row = rt * 16 + quad * 4 + q;
            float z = (acc[t][q] + bias[t] - mstat[row][0]) * mstat[row][1] * gg + bb;
            float h = z / (1.f + __expf(-z));
            Abf[row * 264 + col] = f2bf(h);
        }
    }
    __syncthreads();

    // ---- GEMM2: out = h @ Wn2 + bn2 + x ----
    f32x4 o[8];
#pragma unroll
    for (int t = 0; t < 8; t++) o[t] = (f32x4){0.f, 0.f, 0.f, 0.f};
    for (int ks = 0; ks < 8; ks++) {
        bf16x8 a = *(const bf16x8*)&Abf[arow * 264 + ks * 32 + kq];
        const bf16x8* bp =
            (const bf16x8*)&Bsw2[(size_t)(((ks * 16 + cg * 8) * 64) + lane) * 8];
#pragma unroll
        for (int t = 0; t < 8; t++)
            o[t] = __builtin_amdgcn_mfma_f32_16x16x32_bf16(a, bp[t * 64], o[t], 0, 0, 0);
    }
#pragma unroll
    for (int t = 0; t < 8; t++) {
        int col = cg * 128 + t * 16 + lcol;
        float ob = bn2[col];
#pragma unroll
        for (int q = 0; q < 4; q++) {
            int row = rt * 16 + quad * 4 + q;
            int n = n0 + row;
            if (n < N)
                out[(size_t)n * 256 + col] = o[t][q] + ob + x[(size_t)n * 256 + col];
        }
    }
}

// ---------------------------------------------------------------------------
extern "C" void kernel_launch(void* const* d_in, const int* in_sizes, int n_in,
                              void* d_out, int out_size, void* d_ws, size_t ws_size,
                              hipStream_t stream)
{
    const float* x      = (const float*)d_in[0];
    const float* rbf    = (const float*)d_in[1];
    const float* factor = (const float*)d_in[2];
    const float* sph0   = (const float*)d_in[3];
    const float* sph1   = (const float*)d_in[4];
    const float* Wd     = (const float*)d_in[5];
    const float* bd     = (const float*)d_in[6];
    const float* Wu0    = (const float*)d_in[7];
    const float* bu0    = (const float*)d_in[8];
    const float* Wu1    = (const float*)d_in[9];
    const float* Wuh    = (const float*)d_in[10];
    const float* Wn1    = (const float*)d_in[11];
    const float* bn1    = (const float*)d_in[12];
    const float* lng    = (const float*)d_in[13];
    const float* lnb    = (const float*)d_in[14];
    const float* Wn2    = (const float*)d_in[15];
    const float* bn2    = (const float*)d_in[16];
    const int*   jidx   = (const int*)d_in[17];
    const int*   iidx   = (const int*)d_in[18];
    float* out = (float*)d_out;

    int N = in_sizes[0] / 256;
    int E = in_sizes[17];

    float* ws   = (float*)d_ws;
    float* xp   = ws;                        // [N,64]
    float* agg0 = xp   + (size_t)N * 64;     // [N,64]
    float* agg1 = agg0 + (size_t)N * 64;     // [N,3,64]
    float* aggh = agg1 + (size_t)N * 192;    // [N,5,64]
    float* node = aggh + (size_t)N * 320;    // [N,384]
    // swizzled bf16 weights after node (one-time conversion per launch)
    unsigned short* Bsw1 = (unsigned short*)(node + (size_t)N * 384); // 12*16*64*8
    unsigned short* Bsw2 = Bsw1 + 12 * 16 * 64 * 8;                    // 8*16*64*8

    // CSR scratch aliased onto the node buffer (dead before k_node writes it).
    int* counts  = (int*)node;               // [N]
    int* rowptr  = counts + (N + 1);         // [N+1]
    int* cursor  = rowptr + (N + 1);         // [N]
    int* edge_id = cursor + (N + 1);         // [E]

    hipMemsetAsync(counts, 0, (size_t)(N + 1) * sizeof(int), stream);

    k_swz<<<dim3(48), dim3(256), 0, stream>>>(Wn1, Bsw1, 384);
    k_swz<<<dim3(32), dim3(256), 0, stream>>>(Wn2, Bsw2, 256);
    k_down<<<dim3((N + KD_NODES - 1) / KD_NODES), dim3(256), 0, stream>>>(
        x, Wd, bd, xp, N);
    k_hist<<<dim3((E + 255) / 256), dim3(256), 0, stream>>>(iidx, counts, E);
    k_scan<<<dim3(1), dim3(1024), 0, stream>>>(counts, rowptr, cursor, N);
    k_scatter_ids<<<dim3((E + 255) / 256), dim3(256), 0, stream>>>(
        iidx, cursor, edge_id, E);
    k_gather<<<dim3((N + 3) / 4), dim3(256), 0, stream>>>(
        xp, rbf, factor, sph0, sph1, jidx, rowptr, edge_id,
        agg0, agg1, aggh, N);
    k_node<<<dim3((N + C1_NODES - 1) / C1_NODES), dim3(256), 0, stream>>>(
        xp, agg0, agg1, aggh, Wu0, bu0, Wu1, Wuh, node, N);
    k_final<<<dim3((N + 31) / 32), dim3(256), 0, stream>>>(
        node, Bsw1, bn1, lng, lnb, Bsw2, bn2, x, out, N);
}